// Round 12
// baseline (255.399 us; speedup 1.0000x reference)
//
#include <hip/hip_runtime.h>
#include <math.h>

#define N_QUBITS 24
#define N_BLOCKS 4
#define NSTATE (1 << N_QUBITS)

// Qubit q <-> flat-index bit (23 - q).
// Per block (by commutation): RY(0); for q=1..23: RY(q); CNOT(q-1,q)
// Ping-pong buffers, alternating layouts (race-free: src != dst).
//   standard: addr = e23..e0
//   pi:       addr = e[6..14]<<15 | H<<6 | e[0..5],  H bit k = e(15+k)
// P1  (qubits 0..8):  d_out std (scattered reads) -> d_ws pi (contiguous)  [R9 proven]
// P23 (qubits 9..23): d_ws pi (scattered reads) -> d_out std (contiguous)
//   R12: T1 chunked by (e13,e14) = reg bits 4,5 on BOTH sides -> 4 rounds x
//   8K floats = 32 KiB LDS -> 3 wg/CU (was 2). L1 regs = (e5..8, e13, e14);
//   q15..18 reg gates, q19..23 shfl gates (masks 16,8,4,2,1). Both T1 sides
//   keep e0..4 in addr low bits -> <=2-way banks, no swizzle needed.

// ---- 64-reg gate helpers ----
template <int B>
__device__ __forceinline__ void pair_bit(float (&a)[64], float s, float c, int swap) {
#pragma unroll
    for (int g = 0; g < 32; ++g) {
        int r0 = ((g >> B) << (B + 1)) | (g & ((1 << B) - 1));
        int r1 = r0 | (1 << B);
        float v0 = a[r0], v1 = a[r1];
        float o0 = c * v0 - s * v1;
        float o1 = s * v0 + c * v1;
        a[r0] = swap ? o1 : o0;
        a[r1] = swap ? o0 : o1;
    }
}
// Fused RY(tgt = reg bit BT) then CNOT(ctrl = reg bit BT+1, tgt = reg bit BT).
template <int BT>
__device__ __forceinline__ void quad_gate(float (&a)[64], float s, float c) {
#pragma unroll
    for (int g = 0; g < 16; ++g) {
        int lo  = g & ((1 << BT) - 1);
        int r00 = ((g >> BT) << (BT + 2)) | lo;
        int r01 = r00 | (1 << BT);
        int r10 = r00 | (2 << BT);
        int r11 = r00 | (3 << BT);
        float v00 = a[r00], v01 = a[r01], v10 = a[r10], v11 = a[r11];
        a[r00] = c * v00 - s * v01;
        a[r01] = s * v00 + c * v01;
        a[r10] = s * v10 + c * v11;   // ctrl=1 half: RY then swap (CNOT)
        a[r11] = c * v10 - s * v11;
    }
}

// ---------------- Pass 1 (std -> pi): qubits 0..8 (bits 15..23) ----------------
// R9-proven (~32 us). 512 thr x 64 regs, 64 KiB LDS, contiguous pi writes.
__global__ __launch_bounds__(512)
void pass1_pi_kernel(const float* __restrict__ src, float* __restrict__ dst,
                     const float* __restrict__ angles, int blk_b) {
    __shared__ float lds[16384];
    const int tid  = threadIdx.x;
    const int lane = tid & 63;
    const int w    = tid >> 6;
    const int blk  = blockIdx.x;                 // e6..14
    const float* ang = angles + blk_b * N_QUBITS;
    const size_t lowbase = ((size_t)blk << 6) | (size_t)lane;

    float a[64];
#pragma unroll
    for (int r = 0; r < 64; ++r)
        a[r] = src[((size_t)((r << 3) | w) << 15) | lowbase];

    float s, c;
    sincosf(0.5f * ang[0], &s, &c); pair_bit<5>(a, s, c, 0);
    sincosf(0.5f * ang[1], &s, &c); quad_gate<4>(a, s, c);
    sincosf(0.5f * ang[2], &s, &c); quad_gate<3>(a, s, c);
    sincosf(0.5f * ang[3], &s, &c); quad_gate<2>(a, s, c);
    sincosf(0.5f * ang[4], &s, &c); quad_gate<1>(a, s, c);
    sincosf(0.5f * ang[5], &s, &c); quad_gate<0>(a, s, c);

#pragma unroll
    for (int cb = 0; cb < 2; ++cb) {
        if (cb) __syncthreads();
#pragma unroll
        for (int rr = 0; rr < 32; ++rr)
            lds[(rr << 9) | (w << 6) | lane] = a[(cb << 5) | rr];
        __syncthreads();
#pragma unroll
        for (int q = 0; q < 32; ++q) {
            int h = (((q >> 1) & 1) << 13) | ((q & 1) << 12) | (w << 9)
                  | (((q >> 4) & 1) << 8) | (((q >> 3) & 1) << 7) | (((q >> 2) & 1) << 6)
                  | lane;
            a[(cb << 5) | q] = lds[h];
        }
    }

    sincosf(0.5f * ang[6], &s, &c); pair_bit<4>(a, s, c, w & 1);
    sincosf(0.5f * ang[7], &s, &c); quad_gate<3>(a, s, c);
    sincosf(0.5f * ang[8], &s, &c); quad_gate<2>(a, s, c);

    // store pi: H bit k = e(15+k) (identity ordering)
#pragma unroll
    for (int r = 0; r < 64; ++r) {
        int H = (((r >> 5) & 1) << 8) | (((r >> 1) & 1) << 7) | ((r & 1) << 6) | (w << 3)
              | (((r >> 4) & 1) << 2) | (((r >> 3) & 1) << 1) | ((r >> 2) & 1);
        dst[((size_t)blk << 15) | (H << 6) | lane] = a[r];
    }
}

// ---------------- Pass 2+3 tail: qubits 9..23 on a 32768-float chunk -----------
// L0 (entry): regs = (e9..13 @ bits0..4, e14@5), w = e6..8, lane = e0..5.
// T1 (4 rounds chunked by e13=reg4, e14=reg5 on both sides; identity addr):
//   L1: regs k = (e5,e6,e7,e8 @ bits0..3, e13@4, e14@5),
//       lane = (e0..4, e9@5), w = e10..12.
// Gates: q9..14 reg (L0); q15 pair (ctrl e9 = lane5); q16..18 quad reg;
//        q19 shfl mask16 (ctrl e5 = reg bit0); q20..23 shfl masks 8/4/2/1.
template <bool SQUARE>
__device__ __forceinline__ void p23_tail(float (&a)[64], float* __restrict__ lds,
                                         float* __restrict__ base, const float* ang,
                                         int lane, int w, int c15) {
    float s, c;
    // phase 1: qubits 9..14 on L0 regs
    sincosf(0.5f * ang[9], &s, &c);  pair_bit<5>(a, s, c, c15);   // q9: tgt e14, ctrl e15
    sincosf(0.5f * ang[10], &s, &c); quad_gate<4>(a, s, c);       // q10: tgt e13 ctrl e14
    sincosf(0.5f * ang[11], &s, &c); quad_gate<3>(a, s, c);
    sincosf(0.5f * ang[12], &s, &c); quad_gate<2>(a, s, c);
    sincosf(0.5f * ang[13], &s, &c); quad_gate<1>(a, s, c);
    sincosf(0.5f * ang[14], &s, &c); quad_gate<0>(a, s, c);       // q14: tgt e9 ctrl e10

    // T1: 4 rounds over x = (e14<<1)|e13; per round both sides touch regs
    // {x<<4 .. x<<4+15} only (clobber-free). 8192 floats/round.
    // write h' = lane | w<<6 | j<<9              (j = e9..12)
    // read  h' = (lane&31) | (m&1)<<5 | (m>>1)<<6 | (lane>>5)<<9 | w<<10
    // Both sides: h' low5 = e0..4 = lane low5 -> 2-way banks (free).
#pragma unroll
    for (int x = 0; x < 4; ++x) {
        if (x) __syncthreads();
#pragma unroll
        for (int j = 0; j < 16; ++j)
            lds[lane | (w << 6) | (j << 9)] = a[(x << 4) | j];
        __syncthreads();
#pragma unroll
        for (int m = 0; m < 16; ++m)
            a[(x << 4) | m] = lds[(lane & 31) | ((m & 1) << 5) | ((m >> 1) << 6)
                                  | ((lane >> 5) << 9) | (w << 10)];
    }

    // phase 2: qubits 15..18 on L1 regs (k0..k3 = e5..e8)
    sincosf(0.5f * ang[15], &s, &c); pair_bit<3>(a, s, c, (lane >> 5) & 1); // q15: tgt e8 ctrl e9
    sincosf(0.5f * ang[16], &s, &c); quad_gate<2>(a, s, c);                 // q16: tgt e7 ctrl e8
    sincosf(0.5f * ang[17], &s, &c); quad_gate<1>(a, s, c);                 // q17: tgt e6 ctrl e7
    sincosf(0.5f * ang[18], &s, &c); quad_gate<0>(a, s, c);                 // q18: tgt e5 ctrl e6

    // phase 3: shfl gates. Butterfly: out = A*v + B*partner.
    //   gam=0: (A,B) = (c, tau? s : -s);  gam=1: (A,B) = (tau? -s : s, c)
    // q19: tgt e4 (mask 16), ctrl e5 = reg bit0 (per-reg)
    sincosf(0.5f * ang[19], &s, &c);
    {
        const int tau = (lane >> 4) & 1;
        const float A0 = c,            B0 = tau ? s : -s;   // gam = 0 (even regs)
        const float A1 = tau ? -s : s, B1 = c;              // gam = 1 (odd regs)
#pragma unroll
        for (int r = 0; r < 64; ++r) {
            float p = __shfl_xor(a[r], 16);
            float A = (r & 1) ? A1 : A0;
            float B = (r & 1) ? B1 : B0;
            a[r] = A * a[r] + B * p;
        }
    }
    // q20..23: tgt = lane bit bt (3..0), ctrl = lane bit bt+1
#pragma unroll
    for (int q = 20; q <= 23; ++q) {
        const int bt = 23 - q;                 // 3..0
        sincosf(0.5f * ang[q], &s, &c);
        const int tau = (lane >> bt) & 1;
        const int gam = (lane >> (bt + 1)) & 1;
        const float A = gam ? (tau ? -s : s) : c;
        const float B = gam ? c : (tau ? s : -s);
#pragma unroll
        for (int r = 0; r < 64; ++r) {
            float p = __shfl_xor(a[r], 1 << bt);
            a[r] = A * a[r] + B * p;
        }
    }

    if (SQUARE) {
#pragma unroll
        for (int r = 0; r < 64; ++r) a[r] *= a[r];
    }

    // store STANDARD from L1:
    // addr = e0..4(lane&31) | e5..8(k&15)<<5 | e9(lane5)<<9 | e10..12(w)<<10
    //      | e13(k4)<<13 | e14(k5)<<14   -> 2 x 128B segments per wave-instr
#pragma unroll
    for (int k = 0; k < 64; ++k)
        base[(lane & 31) | ((k & 15) << 5) | (((lane >> 5) & 1) << 9)
             | (w << 10) | (((k >> 4) & 1) << 13) | (((k >> 5) & 1) << 14)] = a[k];
}

// P23: read pi from src, write standard to dst. H identity-ordered -> chunk<<15
// is the standard high-bit base.
template <bool SQUARE>
__global__ __launch_bounds__(512)
void pass23_pi_kernel(const float* __restrict__ src, float* __restrict__ dst,
                      const float* __restrict__ angles, int blk_b) {
    __shared__ float lds[8192];
    const int tid  = threadIdx.x;
    const int lane = tid & 63;
    const int w    = tid >> 6;
    const int chunk = blockIdx.x;                // = H, H_k = e(15+k)
    float* __restrict__ base = dst + ((size_t)chunk << 15);
    const int c15 = chunk & 1;                   // e15
    const float* ang = angles + blk_b * N_QUBITS;

    float a[64];
    // read pi: addr = (e6..14 = r<<3|w)<<15 | chunk<<6 | lane  (L0 entry layout)
#pragma unroll
    for (int r = 0; r < 64; ++r)
        a[r] = src[((size_t)((r << 3) | w) << 15) | ((size_t)chunk << 6) | (size_t)lane];

    p23_tail<SQUARE>(a, lds, base, ang, lane, w, c15);
}

// Block 0 fused: after qubits 0..8 from |0..0>, state = f9[e15..23] * delta(e0..14).
// f9 index bit k = e(15+k) = chunk bit k -> amp = f[chunk].
__global__ __launch_bounds__(512)
void pass23_init_kernel(float* __restrict__ dst, const float* __restrict__ angles) {
    __shared__ float lds[8192];
    const int tid  = threadIdx.x;
    const int lane = tid & 63;
    const int w    = tid >> 6;
    const int chunk = blockIdx.x;
    float* __restrict__ base = dst + ((size_t)chunk << 15);
    const float* ang = angles;                   // block 0
    float s, c;

    float* f = lds;
    f[tid] = 0.0f;
    __syncthreads();
    if (tid == 0) f[0] = 1.0f;
    __syncthreads();
    sincosf(0.5f * ang[0], &s, &c);
    if (tid < 256) {
        float v0 = f[tid], v1 = f[tid | 256];
        f[tid]       = c * v0 - s * v1;
        f[tid | 256] = s * v0 + c * v1;
    }
    __syncthreads();
    for (int q = 1; q <= 8; ++q) {
        sincosf(0.5f * ang[q], &s, &c);
        int bt = 8 - q;
        if (tid < 128) {
            int lo  = tid & ((1 << bt) - 1);
            int r00 = ((tid >> bt) << (bt + 2)) | lo;
            int r01 = r00 | (1 << bt);
            int r10 = r00 | (2 << bt);
            int r11 = r00 | (3 << bt);
            float v00 = f[r00], v01 = f[r01], v10 = f[r10], v11 = f[r11];
            f[r00] = c * v00 - s * v01;
            f[r01] = s * v00 + c * v01;
            f[r10] = s * v10 + c * v11;
            f[r11] = c * v10 - s * v11;
        }
        __syncthreads();
    }
    const float amp = f[chunk];
    __syncthreads();                             // lds reused by the tail

    float a[64];
#pragma unroll
    for (int r = 0; r < 64; ++r) a[r] = 0.0f;
    if (tid == 0) a[0] = amp;                    // element (e0..14)=0 -> r=0, w=0, lane=0

    p23_tail<false>(a, lds, base, ang, lane, w, chunk & 1);
}

extern "C" void kernel_launch(void* const* d_in, const int* in_sizes, int n_in,
                              void* d_out, int out_size, void* d_ws, size_t ws_size,
                              hipStream_t stream) {
    const float* angles = (const float*)d_in[0];
    float* out = (float*)d_out;
    float* ws  = (float*)d_ws;

    pass23_init_kernel<<<NSTATE >> 15, 512, 0, stream>>>(out, angles);

    for (int b = 1; b < N_BLOCKS; ++b) {
        const bool last = (b == N_BLOCKS - 1);
        pass1_pi_kernel<<<NSTATE >> 15, 512, 0, stream>>>(out, ws, angles, b);
        if (last)
            pass23_pi_kernel<true><<<NSTATE >> 15, 512, 0, stream>>>(ws, out, angles, b);
        else
            pass23_pi_kernel<false><<<NSTATE >> 15, 512, 0, stream>>>(ws, out, angles, b);
    }
}

// Round 13
// 226.899 us; speedup vs baseline: 1.1256x; 1.1256x over previous
//
#include <hip/hip_runtime.h>
#include <math.h>

#define N_QUBITS 24
#define N_BLOCKS 4
#define NSTATE (1 << N_QUBITS)

// Qubit q <-> flat-index bit (23 - q).
// Per block (by commutation): RY(0); for q=1..23: RY(q); CNOT(q-1,q)
// Ping-pong buffers, alternating layouts (race-free: src != dst).
//   standard: addr = e23..e0
//   pi2:      addr = blk<<15 | G<<5 | e0..4,  blk = e5..13, G bit k = e(14+k)
// P1  (qubits 0..9):  d_out std (scattered reads) -> d_ws pi2 (contiguous)
//     512 thr x 64 regs, T1 4 rounds chunked by (e22,e23)=reg bits 4,5, 32 KiB.
// P23 (qubits 10..23): d_ws pi2 (scattered reads) -> d_out std (contiguous)
//     512 thr x 32 regs (VGPR<=64 -> 32 waves/CU, 4 wg), span e0..e13 only;
//     CNOT(9,10) ctrl e14 = chunk bit 0. T1 2 rounds chunked by e13=reg bit 4,
//     32 KiB LDS, 3 barriers. q19..23 are shfl gates (masks 16,8,4,2,1).
// Block 0 replaced by init: in-LDS 10-qubit sim (f10) + P23 tail.

// ---- 64-reg gate helpers ----
template <int B>
__device__ __forceinline__ void pair_bit(float (&a)[64], float s, float c, int swap) {
#pragma unroll
    for (int g = 0; g < 32; ++g) {
        int r0 = ((g >> B) << (B + 1)) | (g & ((1 << B) - 1));
        int r1 = r0 | (1 << B);
        float v0 = a[r0], v1 = a[r1];
        float o0 = c * v0 - s * v1;
        float o1 = s * v0 + c * v1;
        a[r0] = swap ? o1 : o0;
        a[r1] = swap ? o0 : o1;
    }
}
template <int BT>
__device__ __forceinline__ void quad_gate(float (&a)[64], float s, float c) {
#pragma unroll
    for (int g = 0; g < 16; ++g) {
        int lo  = g & ((1 << BT) - 1);
        int r00 = ((g >> BT) << (BT + 2)) | lo;
        int r01 = r00 | (1 << BT);
        int r10 = r00 | (2 << BT);
        int r11 = r00 | (3 << BT);
        float v00 = a[r00], v01 = a[r01], v10 = a[r10], v11 = a[r11];
        a[r00] = c * v00 - s * v01;
        a[r01] = s * v00 + c * v01;
        a[r10] = s * v10 + c * v11;   // ctrl=1 half: RY then swap (CNOT)
        a[r11] = c * v10 - s * v11;
    }
}
// ---- 32-reg gate helpers ----
template <int B>
__device__ __forceinline__ void pair_bit32(float (&a)[32], float s, float c, int swap) {
#pragma unroll
    for (int g = 0; g < 16; ++g) {
        int r0 = ((g >> B) << (B + 1)) | (g & ((1 << B) - 1));
        int r1 = r0 | (1 << B);
        float v0 = a[r0], v1 = a[r1];
        float o0 = c * v0 - s * v1;
        float o1 = s * v0 + c * v1;
        a[r0] = swap ? o1 : o0;
        a[r1] = swap ? o0 : o1;
    }
}
template <int BT>
__device__ __forceinline__ void quad_gate32(float (&a)[32], float s, float c) {
#pragma unroll
    for (int g = 0; g < 8; ++g) {
        int lo  = g & ((1 << BT) - 1);
        int r00 = ((g >> BT) << (BT + 2)) | lo;
        int r01 = r00 | (1 << BT);
        int r10 = r00 | (2 << BT);
        int r11 = r00 | (3 << BT);
        float v00 = a[r00], v01 = a[r01], v10 = a[r10], v11 = a[r11];
        a[r00] = c * v00 - s * v01;
        a[r01] = s * v00 + c * v01;
        a[r10] = s * v10 + c * v11;
        a[r11] = c * v10 - s * v11;
    }
}

// ---------------- Pass 1 (std -> pi2): qubits 0..9 (bits e14..e23) -------------
// Phase A: regs = e18..23, w = e15..17, lane = (e0..4, e14@5); blk = e5..13.
// T1 (4 rounds by x = (e23<<1)|e22 at reg bits 5,4 both sides; identity map):
//   L1: regs k = (e14..17 @0..3, e22@4, e23@5), lane = (e0..4, e18@5), w = e19..21.
// Phase B: q6 (tgt e17 = reg3, ctrl e18 = lane5), q7..q9 quads on bits 2..0.
__global__ __launch_bounds__(512)
void pass1_pi_kernel(const float* __restrict__ src, float* __restrict__ dst,
                     const float* __restrict__ angles, int blk_b) {
    __shared__ float lds[8192];
    const int tid  = threadIdx.x;
    const int lane = tid & 63;
    const int w    = tid >> 6;
    const int blk  = blockIdx.x;                 // e5..13 (9 bits)
    const float* ang = angles + blk_b * N_QUBITS;

    float a[64];
    // read std: addr = r<<18 | w<<15 | (lane5=e14)<<14 | blk<<5 | lane&31
#pragma unroll
    for (int r = 0; r < 64; ++r)
        a[r] = src[((size_t)r << 18) | ((size_t)w << 15) | ((size_t)(lane >> 5) << 14)
                   | ((size_t)blk << 5) | (size_t)(lane & 31)];

    float s, c;
    sincosf(0.5f * ang[0], &s, &c); pair_bit<5>(a, s, c, 0);   // q0: tgt e23
    sincosf(0.5f * ang[1], &s, &c); quad_gate<4>(a, s, c);     // q1: tgt e22 ctrl e23
    sincosf(0.5f * ang[2], &s, &c); quad_gate<3>(a, s, c);
    sincosf(0.5f * ang[3], &s, &c); quad_gate<2>(a, s, c);
    sincosf(0.5f * ang[4], &s, &c); quad_gate<1>(a, s, c);
    sincosf(0.5f * ang[5], &s, &c); quad_gate<0>(a, s, c);     // q5: tgt e18 ctrl e19

    // T1: per round x, 8K floats; write identity h' = lane | w<<6 | j<<9
    // (h' = e0..4 | e14<<5 | e15..17<<6 | e18..21<<9); read per L1 coords.
#pragma unroll
    for (int x = 0; x < 4; ++x) {
        if (x) __syncthreads();
#pragma unroll
        for (int j = 0; j < 16; ++j)
            lds[lane | (w << 6) | (j << 9)] = a[(x << 4) | j];
        __syncthreads();
#pragma unroll
        for (int m = 0; m < 16; ++m)
            a[(x << 4) | m] = lds[(lane & 31) | ((m & 1) << 5) | (((m >> 1) & 7) << 6)
                                  | ((lane >> 5) << 9) | (w << 10)];
    }

    sincosf(0.5f * ang[6], &s, &c); pair_bit<3>(a, s, c, (lane >> 5) & 1); // q6: tgt e17 ctrl e18
    sincosf(0.5f * ang[7], &s, &c); quad_gate<2>(a, s, c);                 // q7: tgt e16 ctrl e17
    sincosf(0.5f * ang[8], &s, &c); quad_gate<1>(a, s, c);                 // q8: tgt e15 ctrl e16
    sincosf(0.5f * ang[9], &s, &c); quad_gate<0>(a, s, c);                 // q9: tgt e14 ctrl e15

    // store pi2: G = (k&15)[e14..17] | e18<<4 | w<<5[e19..21] | (k>>4)<<8[e22,e23]
#pragma unroll
    for (int k = 0; k < 64; ++k) {
        int G = (k & 15) | (((lane >> 5) & 1) << 4) | (w << 5) | ((k >> 4) << 8);
        dst[((size_t)blk << 15) | (G << 5) | (size_t)(lane & 31)] = a[k];
    }
}

// ---------------- Pass 2+3 tail: qubits 10..23 on a 16384-float chunk ----------
// L0 (entry): regs r = e9..13, w = e6..8, lane = e0..5. chunk = e14..23 (identity).
// T1 (2 rounds by e13 = reg bit 4 both sides; identity map):
//   L1: regs k = (e5..8 @0..3, e13@4), lane = (e0..4, e9@5), w = e10..12.
// Gates: q10..14 reg (L0, q10 ctrl e14 = chunk&1); q15 pair (ctrl e9 = lane5);
//        q16..18 quads; q19 shfl mask16 (ctrl e5 = reg bit0); q20..23 shfl.
template <bool SQUARE>
__device__ __forceinline__ void p23_tail(float (&a)[32], float* __restrict__ lds,
                                         float* __restrict__ base, const float* ang,
                                         int lane, int w, int c14) {
    float s, c;
    // phase 1: qubits 10..14 on L0 regs
    sincosf(0.5f * ang[10], &s, &c); pair_bit32<4>(a, s, c, c14);  // q10: tgt e13, ctrl e14
    sincosf(0.5f * ang[11], &s, &c); quad_gate32<3>(a, s, c);      // q11: tgt e12 ctrl e13
    sincosf(0.5f * ang[12], &s, &c); quad_gate32<2>(a, s, c);
    sincosf(0.5f * ang[13], &s, &c); quad_gate32<1>(a, s, c);
    sincosf(0.5f * ang[14], &s, &c); quad_gate32<0>(a, s, c);      // q14: tgt e9 ctrl e10

    // T1: rounds x = e13; write identity h' = lane | w<<6 | j<<9 (h' = e0..12)
#pragma unroll
    for (int x = 0; x < 2; ++x) {
        if (x) __syncthreads();
#pragma unroll
        for (int j = 0; j < 16; ++j)
            lds[lane | (w << 6) | (j << 9)] = a[(x << 4) | j];
        __syncthreads();
#pragma unroll
        for (int m = 0; m < 16; ++m)
            a[(x << 4) | m] = lds[(lane & 31) | ((m & 1) << 5) | (((m >> 1) & 7) << 6)
                                  | ((lane >> 5) << 9) | (w << 10)];
    }

    // phase 2: qubits 15..18 on L1 regs (k0..k3 = e5..e8)
    sincosf(0.5f * ang[15], &s, &c); pair_bit32<3>(a, s, c, (lane >> 5) & 1); // q15: tgt e8 ctrl e9
    sincosf(0.5f * ang[16], &s, &c); quad_gate32<2>(a, s, c);                 // q16: tgt e7 ctrl e8
    sincosf(0.5f * ang[17], &s, &c); quad_gate32<1>(a, s, c);                 // q17: tgt e6 ctrl e7
    sincosf(0.5f * ang[18], &s, &c); quad_gate32<0>(a, s, c);                 // q18: tgt e5 ctrl e6

    // phase 3: shfl gates. Butterfly: out = A*v + B*partner.
    //   gam=0: (A,B) = (c, tau? s : -s);  gam=1: (A,B) = (tau? -s : s, c)
    // q19: tgt e4 (mask 16), ctrl e5 = reg bit0
    sincosf(0.5f * ang[19], &s, &c);
    {
        const int tau = (lane >> 4) & 1;
        const float A0 = c,            B0 = tau ? s : -s;
        const float A1 = tau ? -s : s, B1 = c;
#pragma unroll
        for (int r = 0; r < 32; ++r) {
            float p = __shfl_xor(a[r], 16);
            float A = (r & 1) ? A1 : A0;
            float B = (r & 1) ? B1 : B0;
            a[r] = A * a[r] + B * p;
        }
    }
    // q20..23: tgt = lane bit bt (3..0), ctrl = lane bit bt+1
#pragma unroll
    for (int q = 20; q <= 23; ++q) {
        const int bt = 23 - q;                 // 3..0
        sincosf(0.5f * ang[q], &s, &c);
        const int tau = (lane >> bt) & 1;
        const int gam = (lane >> (bt + 1)) & 1;
        const float A = gam ? (tau ? -s : s) : c;
        const float B = gam ? c : (tau ? s : -s);
#pragma unroll
        for (int r = 0; r < 32; ++r) {
            float p = __shfl_xor(a[r], 1 << bt);
            a[r] = A * a[r] + B * p;
        }
    }

    if (SQUARE) {
#pragma unroll
        for (int r = 0; r < 32; ++r) a[r] *= a[r];
    }

    // store STANDARD from L1 (14-bit in-chunk addr):
    // addr = e0..4 | e5..8(k&15)<<5 | e9(lane5)<<9 | e10..12(w)<<10 | e13(k4)<<13
#pragma unroll
    for (int k = 0; k < 32; ++k)
        base[(lane & 31) | ((k & 15) << 5) | (((lane >> 5) & 1) << 9)
             | (w << 10) | (((k >> 4) & 1) << 13)] = a[k];
}

// P23: read pi2 from src, write standard to dst. chunk = e14..23 identity.
template <bool SQUARE>
__global__ __launch_bounds__(512, 4)
void pass23_pi_kernel(const float* __restrict__ src, float* __restrict__ dst,
                      const float* __restrict__ angles, int blk_b) {
    __shared__ float lds[8192];
    const int tid  = threadIdx.x;
    const int lane = tid & 63;
    const int w    = tid >> 6;
    const int chunk = blockIdx.x;                // 10 bits, bit k = e(14+k)
    float* __restrict__ base = dst + ((size_t)chunk << 14);
    const int c14 = chunk & 1;                   // e14
    const float* ang = angles + blk_b * N_QUBITS;

    float a[32];
    // read pi2: addr = (blk = r<<4 | w<<1 | e5)<<15 | chunk<<5 | e0..4
#pragma unroll
    for (int r = 0; r < 32; ++r)
        a[r] = src[((size_t)((r << 4) | (w << 1) | (lane >> 5)) << 15)
                   | ((size_t)chunk << 5) | (size_t)(lane & 31)];

    p23_tail<SQUARE>(a, lds, base, ang, lane, w, c14);
}

// Block 0 fused: after qubits 0..9 from |0..0>, state = f10[e14..23] * delta(e0..13).
// f10 (1024 amps) computed in LDS; f10 index bit k = e(14+k) = chunk bit k.
__global__ __launch_bounds__(512, 4)
void pass23_init_kernel(float* __restrict__ dst, const float* __restrict__ angles) {
    __shared__ float lds[8192];
    const int tid  = threadIdx.x;
    const int lane = tid & 63;
    const int w    = tid >> 6;
    const int chunk = blockIdx.x;
    float* __restrict__ base = dst + ((size_t)chunk << 14);
    const float* ang = angles;                   // block 0
    float s, c;

    float* f = lds;
    f[tid] = 0.0f;
    f[tid + 512] = 0.0f;
    __syncthreads();
    if (tid == 0) f[0] = 1.0f;
    __syncthreads();
    // q0: tgt f10 bit 9 (qubit q <-> f10 bit 9-q)
    sincosf(0.5f * ang[0], &s, &c);
    if (tid < 512) {
        float v0 = f[tid], v1 = f[tid | 512];
        f[tid]       = c * v0 - s * v1;
        f[tid | 512] = s * v0 + c * v1;
    }
    __syncthreads();
    for (int q = 1; q <= 9; ++q) {
        sincosf(0.5f * ang[q], &s, &c);
        int bt = 9 - q;                          // 8..0
        if (tid < 256) {
            int lo  = tid & ((1 << bt) - 1);
            int r00 = ((tid >> bt) << (bt + 2)) | lo;
            int r01 = r00 | (1 << bt);
            int r10 = r00 | (2 << bt);
            int r11 = r00 | (3 << bt);
            float v00 = f[r00], v01 = f[r01], v10 = f[r10], v11 = f[r11];
            f[r00] = c * v00 - s * v01;
            f[r01] = s * v00 + c * v01;
            f[r10] = s * v10 + c * v11;
            f[r11] = c * v10 - s * v11;
        }
        __syncthreads();
    }
    const float amp = f[chunk];
    __syncthreads();                             // lds reused by the tail

    float a[32];
#pragma unroll
    for (int r = 0; r < 32; ++r) a[r] = 0.0f;
    if (tid == 0) a[0] = amp;                    // element (e0..13)=0 -> r=0,w=0,lane=0

    p23_tail<false>(a, lds, base, ang, lane, w, chunk & 1);
}

extern "C" void kernel_launch(void* const* d_in, const int* in_sizes, int n_in,
                              void* d_out, int out_size, void* d_ws, size_t ws_size,
                              hipStream_t stream) {
    const float* angles = (const float*)d_in[0];
    float* out = (float*)d_out;
    float* ws  = (float*)d_ws;

    pass23_init_kernel<<<1024, 512, 0, stream>>>(out, angles);

    for (int b = 1; b < N_BLOCKS; ++b) {
        const bool last = (b == N_BLOCKS - 1);
        pass1_pi_kernel<<<512, 512, 0, stream>>>(out, ws, angles, b);
        if (last)
            pass23_pi_kernel<true><<<1024, 512, 0, stream>>>(ws, out, angles, b);
        else
            pass23_pi_kernel<false><<<1024, 512, 0, stream>>>(ws, out, angles, b);
    }
}

// Round 14
// 224.302 us; speedup vs baseline: 1.1386x; 1.0116x over previous
//
#include <hip/hip_runtime.h>
#include <math.h>

#define N_QUBITS 24
#define N_BLOCKS 4
#define NSTATE (1 << N_QUBITS)

// Qubit q <-> flat-index bit (23 - q).
// Per block (by commutation): RY(0); for q=1..23: RY(q); CNOT(q-1,q)
// Ping-pong buffers, alternating layouts (race-free: src != dst).
//   standard: addr = e23..e0
//   pi2:      addr = blk<<15 | G<<5 | e0..4,  blk = e5..13, G bit k = e(14+k)
// P1  (qubits 0..9):  d_out std (scattered reads) -> d_ws pi2 (contiguous)
//     R14: 1024 thr x 32 regs (VGPR<=64 -> 32 waves/CU), T1 2 rounds chunked
//     by e23 = reg bit 4 both sides, 64 KiB LDS, 3 barriers, q9 = shfl gate.
// P23 (qubits 10..23): d_ws pi2 (scattered reads) -> d_out std (contiguous)
//     [R13 proven] 512 thr x 32 regs, 4 wg/CU, 32 KiB LDS, 3 barriers.
// Block 0 replaced by init: in-LDS 10-qubit sim (f10) + P23 tail.

// ---- 32-reg gate helpers ----
template <int B>
__device__ __forceinline__ void pair_bit32(float (&a)[32], float s, float c, int swap) {
#pragma unroll
    for (int g = 0; g < 16; ++g) {
        int r0 = ((g >> B) << (B + 1)) | (g & ((1 << B) - 1));
        int r1 = r0 | (1 << B);
        float v0 = a[r0], v1 = a[r1];
        float o0 = c * v0 - s * v1;
        float o1 = s * v0 + c * v1;
        a[r0] = swap ? o1 : o0;
        a[r1] = swap ? o0 : o1;
    }
}
// Fused RY(tgt = reg bit BT) then CNOT(ctrl = reg bit BT+1, tgt = reg bit BT).
template <int BT>
__device__ __forceinline__ void quad_gate32(float (&a)[32], float s, float c) {
#pragma unroll
    for (int g = 0; g < 8; ++g) {
        int lo  = g & ((1 << BT) - 1);
        int r00 = ((g >> BT) << (BT + 2)) | lo;
        int r01 = r00 | (1 << BT);
        int r10 = r00 | (2 << BT);
        int r11 = r00 | (3 << BT);
        float v00 = a[r00], v01 = a[r01], v10 = a[r10], v11 = a[r11];
        a[r00] = c * v00 - s * v01;
        a[r01] = s * v00 + c * v01;
        a[r10] = s * v10 + c * v11;   // ctrl=1 half: RY then swap (CNOT)
        a[r11] = c * v10 - s * v11;
    }
}

// ---------------- Pass 1 (std -> pi2): qubits 0..9 (bits e14..e23) -------------
// 1024 thr x 32 regs. L0: regs r = e19..23, w = e15..18, lane = (e0..4, e14@5);
// blk = e5..13 (512 blocks).
// T1 (2 rounds by e23 = reg bit 4 both sides; identity map, conflict-free):
//   L1: regs k = (e15..18 @0..3, e23@4), lane = (e0..4, e14@5), w = e19..22.
// Gates: q0..4 reg (L0); q5 pair (ctrl e19 = w&1); q6..8 quads;
//        q9 shfl mask32 (tgt e14 = lane5, ctrl e15 = reg bit0).
__global__ __launch_bounds__(1024, 2)
void pass1_pi_kernel(const float* __restrict__ src, float* __restrict__ dst,
                     const float* __restrict__ angles, int blk_b) {
    __shared__ float lds[16384];
    const int tid  = threadIdx.x;
    const int lane = tid & 63;
    const int w    = tid >> 6;                   // 0..15 = e15..18
    const int blk  = blockIdx.x;                 // e5..13 (9 bits)
    const float* ang = angles + blk_b * N_QUBITS;

    float a[32];
    // read std: addr = r<<19 | w<<15 | (lane5=e14)<<14 | blk<<5 | lane&31
    // -> 2 x 128B segments per wave instruction
#pragma unroll
    for (int r = 0; r < 32; ++r)
        a[r] = src[((size_t)r << 19) | ((size_t)w << 15) | ((size_t)(lane >> 5) << 14)
                   | ((size_t)blk << 5) | (size_t)(lane & 31)];

    float s, c;
    sincosf(0.5f * ang[0], &s, &c); pair_bit32<4>(a, s, c, 0);  // q0: tgt e23
    sincosf(0.5f * ang[1], &s, &c); quad_gate32<3>(a, s, c);    // q1: tgt e22 ctrl e23
    sincosf(0.5f * ang[2], &s, &c); quad_gate32<2>(a, s, c);    // q2: tgt e21 ctrl e22
    sincosf(0.5f * ang[3], &s, &c); quad_gate32<1>(a, s, c);    // q3: tgt e20 ctrl e21
    sincosf(0.5f * ang[4], &s, &c); quad_gate32<0>(a, s, c);    // q4: tgt e19 ctrl e20

    // T1: rounds x = e23; 16K floats/round (64 KiB).
    // write h = lane | w<<6 | j<<10   (j = e19..22)   [h = e0..4,e14,e15..18,e19..22]
    // read  h = lane | m<<6 | w<<10   (m = e15..18, this w = e19..22)
    // Both sides: h low6 = lane -> conflict-free; regs [x*16, x*16+16) both sides.
#pragma unroll
    for (int x = 0; x < 2; ++x) {
        if (x) __syncthreads();
#pragma unroll
        for (int j = 0; j < 16; ++j)
            lds[lane | (w << 6) | (j << 10)] = a[(x << 4) | j];
        __syncthreads();
#pragma unroll
        for (int m = 0; m < 16; ++m)
            a[(x << 4) | m] = lds[lane | (m << 6) | (w << 10)];
    }

    // phase B: L1 regs k0..3 = e15..18, k4 = e23; w = e19..22
    sincosf(0.5f * ang[5], &s, &c); pair_bit32<3>(a, s, c, w & 1);  // q5: tgt e18 ctrl e19
    sincosf(0.5f * ang[6], &s, &c); quad_gate32<2>(a, s, c);        // q6: tgt e17 ctrl e18
    sincosf(0.5f * ang[7], &s, &c); quad_gate32<1>(a, s, c);        // q7: tgt e16 ctrl e17
    sincosf(0.5f * ang[8], &s, &c); quad_gate32<0>(a, s, c);        // q8: tgt e15 ctrl e16

    // q9: RY tgt e14 (lane bit 5) + CNOT ctrl e15 (reg bit 0): shfl mask 32.
    //   gam=0: (A,B) = (c, tau? s : -s);  gam=1: (A,B) = (tau? -s : s, c)
    sincosf(0.5f * ang[9], &s, &c);
    {
        const int tau = (lane >> 5) & 1;
        const float A0 = c,            B0 = tau ? s : -s;   // gam = 0 (even regs)
        const float A1 = tau ? -s : s, B1 = c;              // gam = 1 (odd regs)
#pragma unroll
        for (int r = 0; r < 32; ++r) {
            float p = __shfl_xor(a[r], 32);
            float A = (r & 1) ? A1 : A0;
            float B = (r & 1) ? B1 : B0;
            a[r] = A * a[r] + B * p;
        }
    }

    // store pi2: G = e14(lane5) | (k&15)<<1 [e15..18] | w<<5 [e19..22] | (k>>4)<<9 [e23]
    // -> per instruction lanes cover addr bits 0..5: 256B contiguous
#pragma unroll
    for (int k = 0; k < 32; ++k) {
        int G = ((lane >> 5) & 1) | ((k & 15) << 1) | (w << 5) | ((k >> 4) << 9);
        dst[((size_t)blk << 15) | (G << 5) | (size_t)(lane & 31)] = a[k];
    }
}

// ---------------- Pass 2+3 tail: qubits 10..23 on a 16384-float chunk ----------
// [R13 proven, unchanged]
// L0 (entry): regs r = e9..13, w = e6..8, lane = e0..5. chunk = e14..23 (identity).
// T1 (2 rounds by e13 = reg bit 4 both sides; identity map):
//   L1: regs k = (e5..8 @0..3, e13@4), lane = (e0..4, e9@5), w = e10..12.
template <bool SQUARE>
__device__ __forceinline__ void p23_tail(float (&a)[32], float* __restrict__ lds,
                                         float* __restrict__ base, const float* ang,
                                         int lane, int w, int c14) {
    float s, c;
    // phase 1: qubits 10..14 on L0 regs
    sincosf(0.5f * ang[10], &s, &c); pair_bit32<4>(a, s, c, c14);  // q10: tgt e13, ctrl e14
    sincosf(0.5f * ang[11], &s, &c); quad_gate32<3>(a, s, c);      // q11: tgt e12 ctrl e13
    sincosf(0.5f * ang[12], &s, &c); quad_gate32<2>(a, s, c);
    sincosf(0.5f * ang[13], &s, &c); quad_gate32<1>(a, s, c);
    sincosf(0.5f * ang[14], &s, &c); quad_gate32<0>(a, s, c);      // q14: tgt e9 ctrl e10

    // T1: rounds x = e13; write identity h = lane | w<<6 | j<<9 (h = e0..12)
#pragma unroll
    for (int x = 0; x < 2; ++x) {
        if (x) __syncthreads();
#pragma unroll
        for (int j = 0; j < 16; ++j)
            lds[lane | (w << 6) | (j << 9)] = a[(x << 4) | j];
        __syncthreads();
#pragma unroll
        for (int m = 0; m < 16; ++m)
            a[(x << 4) | m] = lds[(lane & 31) | ((m & 1) << 5) | (((m >> 1) & 7) << 6)
                                  | ((lane >> 5) << 9) | (w << 10)];
    }

    // phase 2: qubits 15..18 on L1 regs (k0..k3 = e5..e8)
    sincosf(0.5f * ang[15], &s, &c); pair_bit32<3>(a, s, c, (lane >> 5) & 1); // q15: tgt e8 ctrl e9
    sincosf(0.5f * ang[16], &s, &c); quad_gate32<2>(a, s, c);                 // q16: tgt e7 ctrl e8
    sincosf(0.5f * ang[17], &s, &c); quad_gate32<1>(a, s, c);                 // q17: tgt e6 ctrl e7
    sincosf(0.5f * ang[18], &s, &c); quad_gate32<0>(a, s, c);                 // q18: tgt e5 ctrl e6

    // phase 3: shfl gates.
    // q19: tgt e4 (mask 16), ctrl e5 = reg bit0
    sincosf(0.5f * ang[19], &s, &c);
    {
        const int tau = (lane >> 4) & 1;
        const float A0 = c,            B0 = tau ? s : -s;
        const float A1 = tau ? -s : s, B1 = c;
#pragma unroll
        for (int r = 0; r < 32; ++r) {
            float p = __shfl_xor(a[r], 16);
            float A = (r & 1) ? A1 : A0;
            float B = (r & 1) ? B1 : B0;
            a[r] = A * a[r] + B * p;
        }
    }
    // q20..23: tgt = lane bit bt (3..0), ctrl = lane bit bt+1
#pragma unroll
    for (int q = 20; q <= 23; ++q) {
        const int bt = 23 - q;                 // 3..0
        sincosf(0.5f * ang[q], &s, &c);
        const int tau = (lane >> bt) & 1;
        const int gam = (lane >> (bt + 1)) & 1;
        const float A = gam ? (tau ? -s : s) : c;
        const float B = gam ? c : (tau ? s : -s);
#pragma unroll
        for (int r = 0; r < 32; ++r) {
            float p = __shfl_xor(a[r], 1 << bt);
            a[r] = A * a[r] + B * p;
        }
    }

    if (SQUARE) {
#pragma unroll
        for (int r = 0; r < 32; ++r) a[r] *= a[r];
    }

    // store STANDARD from L1 (14-bit in-chunk addr):
    // addr = e0..4 | e5..8(k&15)<<5 | e9(lane5)<<9 | e10..12(w)<<10 | e13(k4)<<13
#pragma unroll
    for (int k = 0; k < 32; ++k)
        base[(lane & 31) | ((k & 15) << 5) | (((lane >> 5) & 1) << 9)
             | (w << 10) | (((k >> 4) & 1) << 13)] = a[k];
}

// P23: read pi2 from src, write standard to dst. chunk = e14..23 identity.
template <bool SQUARE>
__global__ __launch_bounds__(512, 4)
void pass23_pi_kernel(const float* __restrict__ src, float* __restrict__ dst,
                      const float* __restrict__ angles, int blk_b) {
    __shared__ float lds[8192];
    const int tid  = threadIdx.x;
    const int lane = tid & 63;
    const int w    = tid >> 6;
    const int chunk = blockIdx.x;                // 10 bits, bit k = e(14+k)
    float* __restrict__ base = dst + ((size_t)chunk << 14);
    const int c14 = chunk & 1;                   // e14
    const float* ang = angles + blk_b * N_QUBITS;

    float a[32];
    // read pi2: addr = (blk = r<<4 | w<<1 | e5)<<15 | chunk<<5 | e0..4
#pragma unroll
    for (int r = 0; r < 32; ++r)
        a[r] = src[((size_t)((r << 4) | (w << 1) | (lane >> 5)) << 15)
                   | ((size_t)chunk << 5) | (size_t)(lane & 31)];

    p23_tail<SQUARE>(a, lds, base, ang, lane, w, c14);
}

// Block 0 fused: after qubits 0..9 from |0..0>, state = f10[e14..23] * delta(e0..13).
__global__ __launch_bounds__(512, 4)
void pass23_init_kernel(float* __restrict__ dst, const float* __restrict__ angles) {
    __shared__ float lds[8192];
    const int tid  = threadIdx.x;
    const int lane = tid & 63;
    const int w    = tid >> 6;
    const int chunk = blockIdx.x;
    float* __restrict__ base = dst + ((size_t)chunk << 14);
    const float* ang = angles;                   // block 0
    float s, c;

    float* f = lds;
    f[tid] = 0.0f;
    f[tid + 512] = 0.0f;
    __syncthreads();
    if (tid == 0) f[0] = 1.0f;
    __syncthreads();
    sincosf(0.5f * ang[0], &s, &c);
    if (tid < 512) {
        float v0 = f[tid], v1 = f[tid | 512];
        f[tid]       = c * v0 - s * v1;
        f[tid | 512] = s * v0 + c * v1;
    }
    __syncthreads();
    for (int q = 1; q <= 9; ++q) {
        sincosf(0.5f * ang[q], &s, &c);
        int bt = 9 - q;                          // 8..0
        if (tid < 256) {
            int lo  = tid & ((1 << bt) - 1);
            int r00 = ((tid >> bt) << (bt + 2)) | lo;
            int r01 = r00 | (1 << bt);
            int r10 = r00 | (2 << bt);
            int r11 = r00 | (3 << bt);
            float v00 = f[r00], v01 = f[r01], v10 = f[r10], v11 = f[r11];
            f[r00] = c * v00 - s * v01;
            f[r01] = s * v00 + c * v01;
            f[r10] = s * v10 + c * v11;
            f[r11] = c * v10 - s * v11;
        }
        __syncthreads();
    }
    const float amp = f[chunk];
    __syncthreads();                             // lds reused by the tail

    float a[32];
#pragma unroll
    for (int r = 0; r < 32; ++r) a[r] = 0.0f;
    if (tid == 0) a[0] = amp;                    // element (e0..13)=0 -> r=0,w=0,lane=0

    p23_tail<false>(a, lds, base, ang, lane, w, chunk & 1);
}

extern "C" void kernel_launch(void* const* d_in, const int* in_sizes, int n_in,
                              void* d_out, int out_size, void* d_ws, size_t ws_size,
                              hipStream_t stream) {
    const float* angles = (const float*)d_in[0];
    float* out = (float*)d_out;
    float* ws  = (float*)d_ws;

    pass23_init_kernel<<<1024, 512, 0, stream>>>(out, angles);

    for (int b = 1; b < N_BLOCKS; ++b) {
        const bool last = (b == N_BLOCKS - 1);
        pass1_pi_kernel<<<512, 1024, 0, stream>>>(out, ws, angles, b);
        if (last)
            pass23_pi_kernel<true><<<1024, 512, 0, stream>>>(ws, out, angles, b);
        else
            pass23_pi_kernel<false><<<1024, 512, 0, stream>>>(ws, out, angles, b);
    }
}

// Round 15
// 176.084 us; speedup vs baseline: 1.4504x; 1.2738x over previous
//
#include <hip/hip_runtime.h>
#include <math.h>

#define N_QUBITS 24
#define N_BLOCKS 4
#define NSTATE (1 << N_QUBITS)

// Qubit q <-> flat-index bit (23 - q).
// Per block (by commutation): RY(0); for q=1..23: RY(q); CNOT(q-1,q)
// Ping-pong buffers, alternating layouts (race-free: src != dst).
//   standard: addr = e23..e0
//   pi2:      addr = blk<<15 | G<<5 | e0..4,  blk = e5..13, G bit k = e(14+k)
// P1  (qubits 0..9):  d_out std (scattered reads) -> d_ws pi2 (contiguous)
//     1024 thr x 32 regs (VGPR<=64 -> 32 waves/CU), T1 2 rounds chunked by
//     e23 = reg bit 4 both sides, 64 KiB LDS, q9 = shfl gate.
// P23 (qubits 10..23): d_ws pi2 (scattered reads) -> d_out std (contiguous)
//     512 thr x 32 regs, 4 wg/CU, 32 KiB LDS, 3 barriers.
// Block 0 replaced by init: in-LDS 10-qubit sim (f10) + P23 tail.
// R15: per-workgroup LDS sin/cos tables (threads 0..N-1 compute sincosf once;
// gates read via same-address LDS broadcast) — removes 10-24 sincosf/thread.

// ---- 32-reg gate helpers ----
template <int B>
__device__ __forceinline__ void pair_bit32(float (&a)[32], float s, float c, int swap) {
#pragma unroll
    for (int g = 0; g < 16; ++g) {
        int r0 = ((g >> B) << (B + 1)) | (g & ((1 << B) - 1));
        int r1 = r0 | (1 << B);
        float v0 = a[r0], v1 = a[r1];
        float o0 = c * v0 - s * v1;
        float o1 = s * v0 + c * v1;
        a[r0] = swap ? o1 : o0;
        a[r1] = swap ? o0 : o1;
    }
}
// Fused RY(tgt = reg bit BT) then CNOT(ctrl = reg bit BT+1, tgt = reg bit BT).
template <int BT>
__device__ __forceinline__ void quad_gate32(float (&a)[32], float s, float c) {
#pragma unroll
    for (int g = 0; g < 8; ++g) {
        int lo  = g & ((1 << BT) - 1);
        int r00 = ((g >> BT) << (BT + 2)) | lo;
        int r01 = r00 | (1 << BT);
        int r10 = r00 | (2 << BT);
        int r11 = r00 | (3 << BT);
        float v00 = a[r00], v01 = a[r01], v10 = a[r10], v11 = a[r11];
        a[r00] = c * v00 - s * v01;
        a[r01] = s * v00 + c * v01;
        a[r10] = s * v10 + c * v11;   // ctrl=1 half: RY then swap (CNOT)
        a[r11] = c * v10 - s * v11;
    }
}

// ---------------- Pass 1 (std -> pi2): qubits 0..9 (bits e14..e23) -------------
// L0: regs r = e19..23, w = e15..18, lane = (e0..4, e14@5); blk = e5..13.
// T1 (2 rounds by e23 = reg bit 4 both sides; identity map, conflict-free):
//   L1: regs k = (e15..18 @0..3, e23@4), lane = (e0..4, e14@5), w = e19..22.
__global__ __launch_bounds__(1024, 2)
void pass1_pi_kernel(const float* __restrict__ src, float* __restrict__ dst,
                     const float* __restrict__ angles, int blk_b) {
    __shared__ float lds[16384];
    __shared__ float scs[10], scc[10];
    const int tid  = threadIdx.x;
    const int lane = tid & 63;
    const int w    = tid >> 6;                   // 0..15 = e15..18
    const int blk  = blockIdx.x;                 // e5..13 (9 bits)
    const float* ang = angles + blk_b * N_QUBITS;

    if (tid < 10) {
        float s, c;
        sincosf(0.5f * ang[tid], &s, &c);
        scs[tid] = s; scc[tid] = c;
    }

    float a[32];
    // read std: addr = r<<19 | w<<15 | (lane5=e14)<<14 | blk<<5 | lane&31
#pragma unroll
    for (int r = 0; r < 32; ++r)
        a[r] = src[((size_t)r << 19) | ((size_t)w << 15) | ((size_t)(lane >> 5) << 14)
                   | ((size_t)blk << 5) | (size_t)(lane & 31)];
    __syncthreads();                             // table ready

    pair_bit32<4>(a, scs[0], scc[0], 0);         // q0: tgt e23
    quad_gate32<3>(a, scs[1], scc[1]);           // q1: tgt e22 ctrl e23
    quad_gate32<2>(a, scs[2], scc[2]);
    quad_gate32<1>(a, scs[3], scc[3]);
    quad_gate32<0>(a, scs[4], scc[4]);           // q4: tgt e19 ctrl e20

    // T1: rounds x = e23; 16K floats/round (64 KiB).
#pragma unroll
    for (int x = 0; x < 2; ++x) {
        __syncthreads();
#pragma unroll
        for (int j = 0; j < 16; ++j)
            lds[lane | (w << 6) | (j << 10)] = a[(x << 4) | j];
        __syncthreads();
#pragma unroll
        for (int m = 0; m < 16; ++m)
            a[(x << 4) | m] = lds[lane | (m << 6) | (w << 10)];
    }

    // phase B: L1 regs k0..3 = e15..18, k4 = e23; w = e19..22
    pair_bit32<3>(a, scs[5], scc[5], w & 1);     // q5: tgt e18 ctrl e19
    quad_gate32<2>(a, scs[6], scc[6]);           // q6: tgt e17 ctrl e18
    quad_gate32<1>(a, scs[7], scc[7]);           // q7: tgt e16 ctrl e17
    quad_gate32<0>(a, scs[8], scc[8]);           // q8: tgt e15 ctrl e16

    // q9: RY tgt e14 (lane bit 5) + CNOT ctrl e15 (reg bit 0): shfl mask 32.
    {
        const float s = scs[9], c = scc[9];
        const int tau = (lane >> 5) & 1;
        const float A0 = c,            B0 = tau ? s : -s;   // gam = 0 (even regs)
        const float A1 = tau ? -s : s, B1 = c;              // gam = 1 (odd regs)
#pragma unroll
        for (int r = 0; r < 32; ++r) {
            float p = __shfl_xor(a[r], 32);
            float A = (r & 1) ? A1 : A0;
            float B = (r & 1) ? B1 : B0;
            a[r] = A * a[r] + B * p;
        }
    }

    // store pi2: G = e14(lane5) | (k&15)<<1 [e15..18] | w<<5 [e19..22] | (k>>4)<<9 [e23]
#pragma unroll
    for (int k = 0; k < 32; ++k) {
        int G = ((lane >> 5) & 1) | ((k & 15) << 1) | (w << 5) | ((k >> 4) << 9);
        dst[((size_t)blk << 15) | (G << 5) | (size_t)(lane & 31)] = a[k];
    }
}

// ---------------- Pass 2+3 tail: qubits 10..23 on a 16384-float chunk ----------
// L0 (entry): regs r = e9..13, w = e6..8, lane = e0..5. chunk = e14..23 (identity).
// T1 (2 rounds by e13 = reg bit 4 both sides; identity map):
//   L1: regs k = (e5..8 @0..3, e13@4), lane = (e0..4, e9@5), w = e10..12.
// scs/scc indexed by (q - 10).
template <bool SQUARE>
__device__ __forceinline__ void p23_tail(float (&a)[32], float* __restrict__ lds,
                                         float* __restrict__ base,
                                         const float* __restrict__ scs,
                                         const float* __restrict__ scc,
                                         int lane, int w, int c14) {
    // phase 1: qubits 10..14 on L0 regs
    pair_bit32<4>(a, scs[0], scc[0], c14);       // q10: tgt e13, ctrl e14
    quad_gate32<3>(a, scs[1], scc[1]);           // q11: tgt e12 ctrl e13
    quad_gate32<2>(a, scs[2], scc[2]);
    quad_gate32<1>(a, scs[3], scc[3]);
    quad_gate32<0>(a, scs[4], scc[4]);           // q14: tgt e9 ctrl e10

    // T1: rounds x = e13; write identity h = lane | w<<6 | j<<9 (h = e0..12)
#pragma unroll
    for (int x = 0; x < 2; ++x) {
        if (x) __syncthreads();
#pragma unroll
        for (int j = 0; j < 16; ++j)
            lds[lane | (w << 6) | (j << 9)] = a[(x << 4) | j];
        __syncthreads();
#pragma unroll
        for (int m = 0; m < 16; ++m)
            a[(x << 4) | m] = lds[(lane & 31) | ((m & 1) << 5) | (((m >> 1) & 7) << 6)
                                  | ((lane >> 5) << 9) | (w << 10)];
    }

    // phase 2: qubits 15..18 on L1 regs (k0..k3 = e5..e8)
    pair_bit32<3>(a, scs[5], scc[5], (lane >> 5) & 1);  // q15: tgt e8 ctrl e9
    quad_gate32<2>(a, scs[6], scc[6]);                  // q16: tgt e7 ctrl e8
    quad_gate32<1>(a, scs[7], scc[7]);                  // q17: tgt e6 ctrl e7
    quad_gate32<0>(a, scs[8], scc[8]);                  // q18: tgt e5 ctrl e6

    // phase 3: shfl gates. Butterfly: out = A*v + B*partner.
    // q19: tgt e4 (mask 16), ctrl e5 = reg bit0
    {
        const float s = scs[9], c = scc[9];
        const int tau = (lane >> 4) & 1;
        const float A0 = c,            B0 = tau ? s : -s;
        const float A1 = tau ? -s : s, B1 = c;
#pragma unroll
        for (int r = 0; r < 32; ++r) {
            float p = __shfl_xor(a[r], 16);
            float A = (r & 1) ? A1 : A0;
            float B = (r & 1) ? B1 : B0;
            a[r] = A * a[r] + B * p;
        }
    }
    // q20..23: tgt = lane bit bt (3..0), ctrl = lane bit bt+1
#pragma unroll
    for (int q = 20; q <= 23; ++q) {
        const int bt = 23 - q;                 // 3..0
        const float s = scs[q - 10], c = scc[q - 10];
        const int tau = (lane >> bt) & 1;
        const int gam = (lane >> (bt + 1)) & 1;
        const float A = gam ? (tau ? -s : s) : c;
        const float B = gam ? c : (tau ? s : -s);
#pragma unroll
        for (int r = 0; r < 32; ++r) {
            float p = __shfl_xor(a[r], 1 << bt);
            a[r] = A * a[r] + B * p;
        }
    }

    if (SQUARE) {
#pragma unroll
        for (int r = 0; r < 32; ++r) a[r] *= a[r];
    }

    // store STANDARD from L1 (14-bit in-chunk addr):
    // addr = e0..4 | e5..8(k&15)<<5 | e9(lane5)<<9 | e10..12(w)<<10 | e13(k4)<<13
#pragma unroll
    for (int k = 0; k < 32; ++k)
        base[(lane & 31) | ((k & 15) << 5) | (((lane >> 5) & 1) << 9)
             | (w << 10) | (((k >> 4) & 1) << 13)] = a[k];
}

// P23: read pi2 from src, write standard to dst. chunk = e14..23 identity.
template <bool SQUARE>
__global__ __launch_bounds__(512, 4)
void pass23_pi_kernel(const float* __restrict__ src, float* __restrict__ dst,
                      const float* __restrict__ angles, int blk_b) {
    __shared__ float lds[8192];
    __shared__ float scs[14], scc[14];
    const int tid  = threadIdx.x;
    const int lane = tid & 63;
    const int w    = tid >> 6;
    const int chunk = blockIdx.x;                // 10 bits, bit k = e(14+k)
    float* __restrict__ base = dst + ((size_t)chunk << 14);
    const int c14 = chunk & 1;                   // e14
    const float* ang = angles + blk_b * N_QUBITS;

    if (tid < 14) {
        float s, c;
        sincosf(0.5f * ang[10 + tid], &s, &c);
        scs[tid] = s; scc[tid] = c;
    }

    float a[32];
    // read pi2: addr = (blk = r<<4 | w<<1 | e5)<<15 | chunk<<5 | e0..4
#pragma unroll
    for (int r = 0; r < 32; ++r)
        a[r] = src[((size_t)((r << 4) | (w << 1) | (lane >> 5)) << 15)
                   | ((size_t)chunk << 5) | (size_t)(lane & 31)];
    __syncthreads();                             // table ready

    p23_tail<SQUARE>(a, lds, base, scs, scc, lane, w, c14);
}

// Block 0 fused: after qubits 0..9 from |0..0>, state = f10[e14..23] * delta(e0..13).
__global__ __launch_bounds__(512, 4)
void pass23_init_kernel(float* __restrict__ dst, const float* __restrict__ angles) {
    __shared__ float lds[8192];
    __shared__ float scs[24], scc[24];
    const int tid  = threadIdx.x;
    const int lane = tid & 63;
    const int w    = tid >> 6;
    const int chunk = blockIdx.x;
    float* __restrict__ base = dst + ((size_t)chunk << 14);
    const float* ang = angles;                   // block 0

    if (tid < 24) {
        float s, c;
        sincosf(0.5f * ang[tid], &s, &c);
        scs[tid] = s; scc[tid] = c;
    }

    float* f = lds;
    f[tid] = 0.0f;
    f[tid + 512] = 0.0f;
    __syncthreads();
    if (tid == 0) f[0] = 1.0f;
    __syncthreads();
    // q0: tgt f10 bit 9 (qubit q <-> f10 bit 9-q)
    if (tid < 512) {
        float s = scs[0], c = scc[0];
        float v0 = f[tid], v1 = f[tid | 512];
        f[tid]       = c * v0 - s * v1;
        f[tid | 512] = s * v0 + c * v1;
    }
    __syncthreads();
    for (int q = 1; q <= 9; ++q) {
        int bt = 9 - q;                          // 8..0
        if (tid < 256) {
            float s = scs[q], c = scc[q];
            int lo  = tid & ((1 << bt) - 1);
            int r00 = ((tid >> bt) << (bt + 2)) | lo;
            int r01 = r00 | (1 << bt);
            int r10 = r00 | (2 << bt);
            int r11 = r00 | (3 << bt);
            float v00 = f[r00], v01 = f[r01], v10 = f[r10], v11 = f[r11];
            f[r00] = c * v00 - s * v01;
            f[r01] = s * v00 + c * v01;
            f[r10] = s * v10 + c * v11;
            f[r11] = c * v10 - s * v11;
        }
        __syncthreads();
    }
    const float amp = f[chunk];
    __syncthreads();                             // lds reused by the tail

    float a[32];
#pragma unroll
    for (int r = 0; r < 32; ++r) a[r] = 0.0f;
    if (tid == 0) a[0] = amp;                    // element (e0..13)=0 -> r=0,w=0,lane=0

    p23_tail<false>(a, lds, base, scs + 10, scc + 10, lane, w, chunk & 1);
}

extern "C" void kernel_launch(void* const* d_in, const int* in_sizes, int n_in,
                              void* d_out, int out_size, void* d_ws, size_t ws_size,
                              hipStream_t stream) {
    const float* angles = (const float*)d_in[0];
    float* out = (float*)d_out;
    float* ws  = (float*)d_ws;

    pass23_init_kernel<<<1024, 512, 0, stream>>>(out, angles);

    for (int b = 1; b < N_BLOCKS; ++b) {
        const bool last = (b == N_BLOCKS - 1);
        pass1_pi_kernel<<<512, 1024, 0, stream>>>(out, ws, angles, b);
        if (last)
            pass23_pi_kernel<true><<<1024, 512, 0, stream>>>(ws, out, angles, b);
        else
            pass23_pi_kernel<false><<<1024, 512, 0, stream>>>(ws, out, angles, b);
    }
}

// Round 16
// 151.510 us; speedup vs baseline: 1.6857x; 1.1622x over previous
//
#include <hip/hip_runtime.h>
#include <math.h>

#define N_QUBITS 24
#define N_BLOCKS 4
#define NSTATE (1 << N_QUBITS)

// Qubit q <-> flat-index bit (23 - q).
// Per block (by commutation): RY(0); for q=1..23: RY(q); CNOT(q-1,q)
// Ping-pong buffers, alternating layouts (race-free: src != dst).
//   standard: addr = e23..e0
//   pi2:      addr = blk<<15 | G<<5 | e0..4,  blk = e5..13, G bit k = e(14+k)
// Schedule (6 dispatches):
//   fused   : block0 analytic product state x block1 q0..9 -> d_ws pi2 (W only)
//   P23(1)  : d_ws -> d_out ;  P1(2): d_out -> d_ws ;  P23(2): d_ws -> d_out
//   P1(3)   : d_out -> d_ws ;  P23(3)+SQUARE: d_ws -> d_out
// Block0 from delta factorizes: state0[e] = f10[e14..23] * g_c[e0..13],
//   g_c[b] = prod_{q=10..23} r_q(b_{23-q} ^ b_{24-q}),  b_14 := c = e14,
//   r_q(0)=cos(th_q/2), r_q(1)=sin(th_q/2)  [staircase transfer factors].

// ---- 32-reg gate helpers ----
template <int B>
__device__ __forceinline__ void pair_bit32(float (&a)[32], float s, float c, int swap) {
#pragma unroll
    for (int g = 0; g < 16; ++g) {
        int r0 = ((g >> B) << (B + 1)) | (g & ((1 << B) - 1));
        int r1 = r0 | (1 << B);
        float v0 = a[r0], v1 = a[r1];
        float o0 = c * v0 - s * v1;
        float o1 = s * v0 + c * v1;
        a[r0] = swap ? o1 : o0;
        a[r1] = swap ? o0 : o1;
    }
}
// Fused RY(tgt = reg bit BT) then CNOT(ctrl = reg bit BT+1, tgt = reg bit BT).
template <int BT>
__device__ __forceinline__ void quad_gate32(float (&a)[32], float s, float c) {
#pragma unroll
    for (int g = 0; g < 8; ++g) {
        int lo  = g & ((1 << BT) - 1);
        int r00 = ((g >> BT) << (BT + 2)) | lo;
        int r01 = r00 | (1 << BT);
        int r10 = r00 | (2 << BT);
        int r11 = r00 | (3 << BT);
        float v00 = a[r00], v01 = a[r01], v10 = a[r10], v11 = a[r11];
        a[r00] = c * v00 - s * v01;
        a[r01] = s * v00 + c * v01;
        a[r10] = s * v10 + c * v11;   // ctrl=1 half: RY then swap (CNOT)
        a[r11] = c * v10 - s * v11;
    }
}

// Shared pass1 body: from a[] in L0 layout, apply qubits 0..9 of block `ang`,
// store pi2 to dst. L0: regs r = e19..23, w = e15..18, lane = (e0..4, e14@5).
// T1 (2 rounds by e23 = reg bit4 both sides; identity map, conflict-free):
//   L1: regs k = (e15..18 @0..3, e23@4), lane = (e0..4, e14@5), w = e19..22.
__device__ __forceinline__ void p1_body(float (&a)[32], float* __restrict__ lds,
                                        float* __restrict__ dst, int blk,
                                        const float* __restrict__ scs,
                                        const float* __restrict__ scc,
                                        int lane, int w) {
    pair_bit32<4>(a, scs[0], scc[0], 0);         // q0: tgt e23
    quad_gate32<3>(a, scs[1], scc[1]);           // q1: tgt e22 ctrl e23
    quad_gate32<2>(a, scs[2], scc[2]);
    quad_gate32<1>(a, scs[3], scc[3]);
    quad_gate32<0>(a, scs[4], scc[4]);           // q4: tgt e19 ctrl e20

    // T1: rounds x = e23; 16K floats/round (64 KiB LDS).
#pragma unroll
    for (int x = 0; x < 2; ++x) {
        __syncthreads();
#pragma unroll
        for (int j = 0; j < 16; ++j)
            lds[lane | (w << 6) | (j << 10)] = a[(x << 4) | j];
        __syncthreads();
#pragma unroll
        for (int m = 0; m < 16; ++m)
            a[(x << 4) | m] = lds[lane | (m << 6) | (w << 10)];
    }

    pair_bit32<3>(a, scs[5], scc[5], w & 1);     // q5: tgt e18 ctrl e19
    quad_gate32<2>(a, scs[6], scc[6]);           // q6: tgt e17 ctrl e18
    quad_gate32<1>(a, scs[7], scc[7]);           // q7: tgt e16 ctrl e17
    quad_gate32<0>(a, scs[8], scc[8]);           // q8: tgt e15 ctrl e16

    // q9: RY tgt e14 (lane bit 5) + CNOT ctrl e15 (reg bit 0): shfl mask 32.
    {
        const float s = scs[9], c = scc[9];
        const int tau = (lane >> 5) & 1;
        const float A0 = c,            B0 = tau ? s : -s;   // gam = 0 (even regs)
        const float A1 = tau ? -s : s, B1 = c;              // gam = 1 (odd regs)
#pragma unroll
        for (int r = 0; r < 32; ++r) {
            float p = __shfl_xor(a[r], 32);
            float A = (r & 1) ? A1 : A0;
            float B = (r & 1) ? B1 : B0;
            a[r] = A * a[r] + B * p;
        }
    }

    // store pi2: G = e14(lane5) | (k&15)<<1 [e15..18] | w<<5 [e19..22] | (k>>4)<<9 [e23]
#pragma unroll
    for (int k = 0; k < 32; ++k) {
        int G = ((lane >> 5) & 1) | ((k & 15) << 1) | (w << 5) | ((k >> 4) << 9);
        dst[((size_t)blk << 15) | (G << 5) | (size_t)(lane & 31)] = a[k];
    }
}

// ---------------- Pass 1 (std -> pi2): qubits 0..9 of block b ------------------
__global__ __launch_bounds__(1024, 2)
void pass1_pi_kernel(const float* __restrict__ src, float* __restrict__ dst,
                     const float* __restrict__ angles, int blk_b) {
    __shared__ float lds[16384];
    __shared__ float scs[10], scc[10];
    const int tid  = threadIdx.x;
    const int lane = tid & 63;
    const int w    = tid >> 6;                   // 0..15 = e15..18
    const int blk  = blockIdx.x;                 // e5..13 (9 bits)
    const float* ang = angles + blk_b * N_QUBITS;

    if (tid < 10) {
        float s, c;
        sincosf(0.5f * ang[tid], &s, &c);
        scs[tid] = s; scc[tid] = c;
    }

    float a[32];
    // read std: addr = r<<19 | w<<15 | (lane5=e14)<<14 | blk<<5 | lane&31
#pragma unroll
    for (int r = 0; r < 32; ++r)
        a[r] = src[((size_t)r << 19) | ((size_t)w << 15) | ((size_t)(lane >> 5) << 14)
                   | ((size_t)blk << 5) | (size_t)(lane & 31)];
    __syncthreads();                             // table ready

    p1_body(a, lds, dst, blk, scs, scc, lane, w);
}

// ---------------- Fused: block0 analytic + block1 qubits 0..9 -> pi2 -----------
// No global reads. f10 (1024 amps, block0 q0..9) via LDS sim; g via per-thread
// 14-factor product; a[r] = f10[(r<<5)|(w<<1)|e14] * g_c[blk<<5 | e0..4].
__global__ __launch_bounds__(1024, 2)
void fused_init_p1_kernel(float* __restrict__ dst, const float* __restrict__ angles) {
    __shared__ float lds[16384];
    __shared__ float s0[24], c0[24];             // block 0
    __shared__ float s1[10], c1[10];             // block 1
    const int tid  = threadIdx.x;
    const int lane = tid & 63;
    const int w    = tid >> 6;
    const int blk  = blockIdx.x;                 // e5..13

    if (tid < 24) {
        float s, c;
        sincosf(0.5f * angles[tid], &s, &c);
        s0[tid] = s; c0[tid] = c;
    } else if (tid >= 32 && tid < 42) {
        float s, c;
        sincosf(0.5f * angles[N_QUBITS + (tid - 32)], &s, &c);
        s1[tid - 32] = s; c1[tid - 32] = c;
    }

    // f10 sim in lds[0..1023]: index bit k = e(14+k); qubit q -> f bit (9-q).
    float* f = lds;
    f[tid] = 0.0f;
    __syncthreads();
    if (tid == 0) f[0] = 1.0f;
    __syncthreads();
    if (tid < 512) {                             // q0: tgt f bit 9 (e23)
        float s = s0[0], c = c0[0];
        float v0 = f[tid], v1 = f[tid | 512];
        f[tid]       = c * v0 - s * v1;
        f[tid | 512] = s * v0 + c * v1;
    }
    __syncthreads();
    for (int q = 1; q <= 9; ++q) {
        int bt = 9 - q;                          // 8..0
        if (tid < 256) {
            float s = s0[q], c = c0[q];
            int lo  = tid & ((1 << bt) - 1);
            int r00 = ((tid >> bt) << (bt + 2)) | lo;
            int r01 = r00 | (1 << bt);
            int r10 = r00 | (2 << bt);
            int r11 = r00 | (3 << bt);
            float v00 = f[r00], v01 = f[r01], v10 = f[r10], v11 = f[r11];
            f[r00] = c * v00 - s * v01;
            f[r01] = s * v00 + c * v01;
            f[r10] = s * v10 + c * v11;
            f[r11] = c * v10 - s * v11;
        }
        __syncthreads();
    }

    // g_c[low14]: low = blk<<5 | (lane&31) (bits e0..13), chain seed c = e14.
    float gval = 1.0f;
    {
        const int low = (blk << 5) | (lane & 31);
        int prev = (lane >> 5) & 1;              // e14
#pragma unroll
        for (int q = 10; q <= 23; ++q) {
            const int bt = 23 - q;               // 13..0
            const int b = (low >> bt) & 1;
            gval *= (b ^ prev) ? s0[q] : c0[q];
            prev = b;
        }
    }

    // synthesize input amps (L0 layout): chunk = (r<<5)|(w<<1)|e14
    float a[32];
#pragma unroll
    for (int r = 0; r < 32; ++r)
        a[r] = f[(r << 5) | (w << 1) | (lane >> 5)] * gval;
    // (p1_body's first __syncthreads orders these f-reads before T1 overwrites lds)

    p1_body(a, lds, dst, blk, s1, c1, lane, w);
}

// ---------------- Pass 2+3 tail: qubits 10..23 on a 16384-float chunk ----------
// L0 (entry): regs r = e9..13, w = e6..8, lane = e0..5. chunk = e14..23 (identity).
// T1 (2 rounds by e13 = reg bit 4 both sides; identity map):
//   L1: regs k = (e5..8 @0..3, e13@4), lane = (e0..4, e9@5), w = e10..12.
// scs/scc indexed by (q - 10).
template <bool SQUARE>
__device__ __forceinline__ void p23_tail(float (&a)[32], float* __restrict__ lds,
                                         float* __restrict__ base,
                                         const float* __restrict__ scs,
                                         const float* __restrict__ scc,
                                         int lane, int w, int c14) {
    // phase 1: qubits 10..14 on L0 regs
    pair_bit32<4>(a, scs[0], scc[0], c14);       // q10: tgt e13, ctrl e14
    quad_gate32<3>(a, scs[1], scc[1]);           // q11: tgt e12 ctrl e13
    quad_gate32<2>(a, scs[2], scc[2]);
    quad_gate32<1>(a, scs[3], scc[3]);
    quad_gate32<0>(a, scs[4], scc[4]);           // q14: tgt e9 ctrl e10

    // T1: rounds x = e13; write identity h = lane | w<<6 | j<<9 (h = e0..12)
#pragma unroll
    for (int x = 0; x < 2; ++x) {
        if (x) __syncthreads();
#pragma unroll
        for (int j = 0; j < 16; ++j)
            lds[lane | (w << 6) | (j << 9)] = a[(x << 4) | j];
        __syncthreads();
#pragma unroll
        for (int m = 0; m < 16; ++m)
            a[(x << 4) | m] = lds[(lane & 31) | ((m & 1) << 5) | (((m >> 1) & 7) << 6)
                                  | ((lane >> 5) << 9) | (w << 10)];
    }

    // phase 2: qubits 15..18 on L1 regs (k0..k3 = e5..e8)
    pair_bit32<3>(a, scs[5], scc[5], (lane >> 5) & 1);  // q15: tgt e8 ctrl e9
    quad_gate32<2>(a, scs[6], scc[6]);                  // q16: tgt e7 ctrl e8
    quad_gate32<1>(a, scs[7], scc[7]);                  // q17: tgt e6 ctrl e7
    quad_gate32<0>(a, scs[8], scc[8]);                  // q18: tgt e5 ctrl e6

    // phase 3: shfl gates. q19: tgt e4 (mask 16), ctrl e5 = reg bit0
    {
        const float s = scs[9], c = scc[9];
        const int tau = (lane >> 4) & 1;
        const float A0 = c,            B0 = tau ? s : -s;
        const float A1 = tau ? -s : s, B1 = c;
#pragma unroll
        for (int r = 0; r < 32; ++r) {
            float p = __shfl_xor(a[r], 16);
            float A = (r & 1) ? A1 : A0;
            float B = (r & 1) ? B1 : B0;
            a[r] = A * a[r] + B * p;
        }
    }
    // q20..23: tgt = lane bit bt (3..0), ctrl = lane bit bt+1
#pragma unroll
    for (int q = 20; q <= 23; ++q) {
        const int bt = 23 - q;                 // 3..0
        const float s = scs[q - 10], c = scc[q - 10];
        const int tau = (lane >> bt) & 1;
        const int gam = (lane >> (bt + 1)) & 1;
        const float A = gam ? (tau ? -s : s) : c;
        const float B = gam ? c : (tau ? s : -s);
#pragma unroll
        for (int r = 0; r < 32; ++r) {
            float p = __shfl_xor(a[r], 1 << bt);
            a[r] = A * a[r] + B * p;
        }
    }

    if (SQUARE) {
#pragma unroll
        for (int r = 0; r < 32; ++r) a[r] *= a[r];
    }

    // store STANDARD from L1 (14-bit in-chunk addr):
    // addr = e0..4 | e5..8(k&15)<<5 | e9(lane5)<<9 | e10..12(w)<<10 | e13(k4)<<13
#pragma unroll
    for (int k = 0; k < 32; ++k)
        base[(lane & 31) | ((k & 15) << 5) | (((lane >> 5) & 1) << 9)
             | (w << 10) | (((k >> 4) & 1) << 13)] = a[k];
}

// P23: read pi2 from src, write standard to dst. chunk = e14..23 identity.
template <bool SQUARE>
__global__ __launch_bounds__(512, 4)
void pass23_pi_kernel(const float* __restrict__ src, float* __restrict__ dst,
                      const float* __restrict__ angles, int blk_b) {
    __shared__ float lds[8192];
    __shared__ float scs[14], scc[14];
    const int tid  = threadIdx.x;
    const int lane = tid & 63;
    const int w    = tid >> 6;
    const int chunk = blockIdx.x;                // 10 bits, bit k = e(14+k)
    float* __restrict__ base = dst + ((size_t)chunk << 14);
    const int c14 = chunk & 1;                   // e14
    const float* ang = angles + blk_b * N_QUBITS;

    if (tid < 14) {
        float s, c;
        sincosf(0.5f * ang[10 + tid], &s, &c);
        scs[tid] = s; scc[tid] = c;
    }

    float a[32];
    // read pi2: addr = (blk = r<<4 | w<<1 | e5)<<15 | chunk<<5 | e0..4
#pragma unroll
    for (int r = 0; r < 32; ++r)
        a[r] = src[((size_t)((r << 4) | (w << 1) | (lane >> 5)) << 15)
                   | ((size_t)chunk << 5) | (size_t)(lane & 31)];
    __syncthreads();                             // table ready

    p23_tail<SQUARE>(a, lds, base, scs, scc, lane, w, c14);
}

extern "C" void kernel_launch(void* const* d_in, const int* in_sizes, int n_in,
                              void* d_out, int out_size, void* d_ws, size_t ws_size,
                              hipStream_t stream) {
    const float* angles = (const float*)d_in[0];
    float* out = (float*)d_out;
    float* ws  = (float*)d_ws;

    // block 0 (analytic) + block 1 qubits 0..9 -> ws (pi2); no global reads
    fused_init_p1_kernel<<<512, 1024, 0, stream>>>(ws, angles);
    pass23_pi_kernel<false><<<1024, 512, 0, stream>>>(ws, out, angles, 1);

    pass1_pi_kernel<<<512, 1024, 0, stream>>>(out, ws, angles, 2);
    pass23_pi_kernel<false><<<1024, 512, 0, stream>>>(ws, out, angles, 2);

    pass1_pi_kernel<<<512, 1024, 0, stream>>>(out, ws, angles, 3);
    pass23_pi_kernel<true><<<1024, 512, 0, stream>>>(ws, out, angles, 3);
}

// Round 17
// 140.078 us; speedup vs baseline: 1.8233x; 1.0816x over previous
//
#include <hip/hip_runtime.h>
#include <math.h>

#define N_QUBITS 24
#define N_BLOCKS 4
#define NSTATE (1 << N_QUBITS)

// Qubit q <-> flat-index bit (23 - q).
// Per block (by commutation): RY(0); for q=1..23: RY(q); CNOT(q-1,q)
// Ping-pong buffers, alternating layouts (race-free: src != dst).
//   standard: addr = e23..e0
//   pi2:      addr = blk<<15 | G<<5 | e0..4,  blk = e5..13, G bit k = e(14+k)
// Schedule (6 dispatches):
//   fused   : block0 analytic product state x block1 q0..9 -> d_ws pi2 (W only)
//   P23(1)  : d_ws -> d_out ;  P1(2): d_out -> d_ws ;  P23(2): d_ws -> d_out
//   P1(3)   : d_out -> d_ws ;  P23(3)+SQUARE: d_ws -> d_out
// R17: shfl-gates with XOR masks 1/2/8 use DPP (VALU pipe: quad_perm / row_ror:8)
// instead of ds_swizzle -> 96 of 224 DS wave-ops per P23 thread move to VALU.

// ---- DPP lane-xor (masks 1,2,8); ds_swizzle via __shfl_xor otherwise ----
template <int CTRL>
__device__ __forceinline__ float dpp_mov(float v) {
    return __int_as_float(__builtin_amdgcn_update_dpp(
        __float_as_int(v), __float_as_int(v), CTRL, 0xF, 0xF, false));
}
template <int MASK>
__device__ __forceinline__ float xor_lanes(float v) {
    if constexpr (MASK == 1)      return dpp_mov<0xB1>(v);   // quad_perm [1,0,3,2]
    else if constexpr (MASK == 2) return dpp_mov<0x4E>(v);   // quad_perm [2,3,0,1]
    else if constexpr (MASK == 8) return dpp_mov<0x128>(v);  // row_ror:8 == xor 8
    else                          return __shfl_xor(v, MASK);
}

// ---- 32-reg gate helpers ----
template <int B>
__device__ __forceinline__ void pair_bit32(float (&a)[32], float s, float c, int swap) {
#pragma unroll
    for (int g = 0; g < 16; ++g) {
        int r0 = ((g >> B) << (B + 1)) | (g & ((1 << B) - 1));
        int r1 = r0 | (1 << B);
        float v0 = a[r0], v1 = a[r1];
        float o0 = c * v0 - s * v1;
        float o1 = s * v0 + c * v1;
        a[r0] = swap ? o1 : o0;
        a[r1] = swap ? o0 : o1;
    }
}
// Fused RY(tgt = reg bit BT) then CNOT(ctrl = reg bit BT+1, tgt = reg bit BT).
template <int BT>
__device__ __forceinline__ void quad_gate32(float (&a)[32], float s, float c) {
#pragma unroll
    for (int g = 0; g < 8; ++g) {
        int lo  = g & ((1 << BT) - 1);
        int r00 = ((g >> BT) << (BT + 2)) | lo;
        int r01 = r00 | (1 << BT);
        int r10 = r00 | (2 << BT);
        int r11 = r00 | (3 << BT);
        float v00 = a[r00], v01 = a[r01], v10 = a[r10], v11 = a[r11];
        a[r00] = c * v00 - s * v01;
        a[r01] = s * v00 + c * v01;
        a[r10] = s * v10 + c * v11;   // ctrl=1 half: RY then swap (CNOT)
        a[r11] = c * v10 - s * v11;
    }
}
// Fused RY+CNOT lane gate: tgt = lane bit of MASK, ctrl = lane bit of 2*MASK.
template <int MASK>
__device__ __forceinline__ void shfl_gate32(float (&a)[32], float s, float c, int lane) {
    const int tau = (lane & MASK) ? 1 : 0;
    const int gam = (lane & (MASK << 1)) ? 1 : 0;
    const float A = gam ? (tau ? -s : s) : c;
    const float B = gam ? c : (tau ? s : -s);
#pragma unroll
    for (int r = 0; r < 32; ++r) {
        float p = xor_lanes<MASK>(a[r]);
        a[r] = A * a[r] + B * p;
    }
}

// Shared pass1 body: from a[] in L0 layout, apply qubits 0..9 of block `ang`,
// store pi2 to dst. L0: regs r = e19..23, w = e15..18, lane = (e0..4, e14@5).
// T1 (2 rounds by e23 = reg bit4 both sides; identity map, conflict-free):
//   L1: regs k = (e15..18 @0..3, e23@4), lane = (e0..4, e14@5), w = e19..22.
__device__ __forceinline__ void p1_body(float (&a)[32], float* __restrict__ lds,
                                        float* __restrict__ dst, int blk,
                                        const float* __restrict__ scs,
                                        const float* __restrict__ scc,
                                        int lane, int w) {
    pair_bit32<4>(a, scs[0], scc[0], 0);         // q0: tgt e23
    quad_gate32<3>(a, scs[1], scc[1]);           // q1: tgt e22 ctrl e23
    quad_gate32<2>(a, scs[2], scc[2]);
    quad_gate32<1>(a, scs[3], scc[3]);
    quad_gate32<0>(a, scs[4], scc[4]);           // q4: tgt e19 ctrl e20

    // T1: rounds x = e23; 16K floats/round (64 KiB LDS).
#pragma unroll
    for (int x = 0; x < 2; ++x) {
        __syncthreads();
#pragma unroll
        for (int j = 0; j < 16; ++j)
            lds[lane | (w << 6) | (j << 10)] = a[(x << 4) | j];
        __syncthreads();
#pragma unroll
        for (int m = 0; m < 16; ++m)
            a[(x << 4) | m] = lds[lane | (m << 6) | (w << 10)];
    }

    pair_bit32<3>(a, scs[5], scc[5], w & 1);     // q5: tgt e18 ctrl e19
    quad_gate32<2>(a, scs[6], scc[6]);           // q6: tgt e17 ctrl e18
    quad_gate32<1>(a, scs[7], scc[7]);           // q7: tgt e16 ctrl e17
    quad_gate32<0>(a, scs[8], scc[8]);           // q8: tgt e15 ctrl e16

    // q9: RY tgt e14 (lane bit 5) + CNOT ctrl e15 (reg bit 0): shfl mask 32.
    {
        const float s = scs[9], c = scc[9];
        const int tau = (lane >> 5) & 1;
        const float A0 = c,            B0 = tau ? s : -s;   // gam = 0 (even regs)
        const float A1 = tau ? -s : s, B1 = c;              // gam = 1 (odd regs)
#pragma unroll
        for (int r = 0; r < 32; ++r) {
            float p = __shfl_xor(a[r], 32);
            float A = (r & 1) ? A1 : A0;
            float B = (r & 1) ? B1 : B0;
            a[r] = A * a[r] + B * p;
        }
    }

    // store pi2: G = e14(lane5) | (k&15)<<1 [e15..18] | w<<5 [e19..22] | (k>>4)<<9 [e23]
#pragma unroll
    for (int k = 0; k < 32; ++k) {
        int G = ((lane >> 5) & 1) | ((k & 15) << 1) | (w << 5) | ((k >> 4) << 9);
        dst[((size_t)blk << 15) | (G << 5) | (size_t)(lane & 31)] = a[k];
    }
}

// ---------------- Pass 1 (std -> pi2): qubits 0..9 of block b ------------------
__global__ __launch_bounds__(1024, 2)
void pass1_pi_kernel(const float* __restrict__ src, float* __restrict__ dst,
                     const float* __restrict__ angles, int blk_b) {
    __shared__ float lds[16384];
    __shared__ float scs[10], scc[10];
    const int tid  = threadIdx.x;
    const int lane = tid & 63;
    const int w    = tid >> 6;                   // 0..15 = e15..18
    const int blk  = blockIdx.x;                 // e5..13 (9 bits)
    const float* ang = angles + blk_b * N_QUBITS;

    if (tid < 10) {
        float s, c;
        sincosf(0.5f * ang[tid], &s, &c);
        scs[tid] = s; scc[tid] = c;
    }

    float a[32];
    // read std: addr = r<<19 | w<<15 | (lane5=e14)<<14 | blk<<5 | lane&31
#pragma unroll
    for (int r = 0; r < 32; ++r)
        a[r] = src[((size_t)r << 19) | ((size_t)w << 15) | ((size_t)(lane >> 5) << 14)
                   | ((size_t)blk << 5) | (size_t)(lane & 31)];
    __syncthreads();                             // table ready

    p1_body(a, lds, dst, blk, scs, scc, lane, w);
}

// ---------------- Fused: block0 analytic + block1 qubits 0..9 -> pi2 -----------
// No global reads. f10 (1024 amps, block0 q0..9) via LDS sim; g via per-thread
// 14-factor product; a[r] = f10[(r<<5)|(w<<1)|e14] * g_c[blk<<5 | e0..4].
__global__ __launch_bounds__(1024, 2)
void fused_init_p1_kernel(float* __restrict__ dst, const float* __restrict__ angles) {
    __shared__ float lds[16384];
    __shared__ float s0[24], c0[24];             // block 0
    __shared__ float s1[10], c1[10];             // block 1
    const int tid  = threadIdx.x;
    const int lane = tid & 63;
    const int w    = tid >> 6;
    const int blk  = blockIdx.x;                 // e5..13

    if (tid < 24) {
        float s, c;
        sincosf(0.5f * angles[tid], &s, &c);
        s0[tid] = s; c0[tid] = c;
    } else if (tid >= 32 && tid < 42) {
        float s, c;
        sincosf(0.5f * angles[N_QUBITS + (tid - 32)], &s, &c);
        s1[tid - 32] = s; c1[tid - 32] = c;
    }

    // f10 sim in lds[0..1023]: index bit k = e(14+k); qubit q -> f bit (9-q).
    float* f = lds;
    f[tid] = 0.0f;
    __syncthreads();
    if (tid == 0) f[0] = 1.0f;
    __syncthreads();
    if (tid < 512) {                             // q0: tgt f bit 9 (e23)
        float s = s0[0], c = c0[0];
        float v0 = f[tid], v1 = f[tid | 512];
        f[tid]       = c * v0 - s * v1;
        f[tid | 512] = s * v0 + c * v1;
    }
    __syncthreads();
    for (int q = 1; q <= 9; ++q) {
        int bt = 9 - q;                          // 8..0
        if (tid < 256) {
            float s = s0[q], c = c0[q];
            int lo  = tid & ((1 << bt) - 1);
            int r00 = ((tid >> bt) << (bt + 2)) | lo;
            int r01 = r00 | (1 << bt);
            int r10 = r00 | (2 << bt);
            int r11 = r00 | (3 << bt);
            float v00 = f[r00], v01 = f[r01], v10 = f[r10], v11 = f[r11];
            f[r00] = c * v00 - s * v01;
            f[r01] = s * v00 + c * v01;
            f[r10] = s * v10 + c * v11;
            f[r11] = c * v10 - s * v11;
        }
        __syncthreads();
    }

    // g_c[low14]: low = blk<<5 | (lane&31) (bits e0..13), chain seed c = e14.
    float gval = 1.0f;
    {
        const int low = (blk << 5) | (lane & 31);
        int prev = (lane >> 5) & 1;              // e14
#pragma unroll
        for (int q = 10; q <= 23; ++q) {
            const int bt = 23 - q;               // 13..0
            const int b = (low >> bt) & 1;
            gval *= (b ^ prev) ? s0[q] : c0[q];
            prev = b;
        }
    }

    // synthesize input amps (L0 layout): chunk = (r<<5)|(w<<1)|e14
    float a[32];
#pragma unroll
    for (int r = 0; r < 32; ++r)
        a[r] = f[(r << 5) | (w << 1) | (lane >> 5)] * gval;
    // (p1_body's first __syncthreads orders these f-reads before T1 overwrites lds)

    p1_body(a, lds, dst, blk, s1, c1, lane, w);
}

// ---------------- Pass 2+3 tail: qubits 10..23 on a 16384-float chunk ----------
// L0 (entry): regs r = e9..13, w = e6..8, lane = e0..5. chunk = e14..23 (identity).
// T1 (2 rounds by e13 = reg bit 4 both sides; identity map):
//   L1: regs k = (e5..8 @0..3, e13@4), lane = (e0..4, e9@5), w = e10..12.
// scs/scc indexed by (q - 10).
template <bool SQUARE>
__device__ __forceinline__ void p23_tail(float (&a)[32], float* __restrict__ lds,
                                         float* __restrict__ base,
                                         const float* __restrict__ scs,
                                         const float* __restrict__ scc,
                                         int lane, int w, int c14) {
    // phase 1: qubits 10..14 on L0 regs
    pair_bit32<4>(a, scs[0], scc[0], c14);       // q10: tgt e13, ctrl e14
    quad_gate32<3>(a, scs[1], scc[1]);           // q11: tgt e12 ctrl e13
    quad_gate32<2>(a, scs[2], scc[2]);
    quad_gate32<1>(a, scs[3], scc[3]);
    quad_gate32<0>(a, scs[4], scc[4]);           // q14: tgt e9 ctrl e10

    // T1: rounds x = e13; write identity h = lane | w<<6 | j<<9 (h = e0..12)
#pragma unroll
    for (int x = 0; x < 2; ++x) {
        if (x) __syncthreads();
#pragma unroll
        for (int j = 0; j < 16; ++j)
            lds[lane | (w << 6) | (j << 9)] = a[(x << 4) | j];
        __syncthreads();
#pragma unroll
        for (int m = 0; m < 16; ++m)
            a[(x << 4) | m] = lds[(lane & 31) | ((m & 1) << 5) | (((m >> 1) & 7) << 6)
                                  | ((lane >> 5) << 9) | (w << 10)];
    }

    // phase 2: qubits 15..18 on L1 regs (k0..k3 = e5..e8)
    pair_bit32<3>(a, scs[5], scc[5], (lane >> 5) & 1);  // q15: tgt e8 ctrl e9
    quad_gate32<2>(a, scs[6], scc[6]);                  // q16: tgt e7 ctrl e8
    quad_gate32<1>(a, scs[7], scc[7]);                  // q17: tgt e6 ctrl e7
    quad_gate32<0>(a, scs[8], scc[8]);                  // q18: tgt e5 ctrl e6

    // phase 3: lane gates. q19: tgt e4 (mask 16), ctrl e5 = reg bit0 (special)
    {
        const float s = scs[9], c = scc[9];
        const int tau = (lane >> 4) & 1;
        const float A0 = c,            B0 = tau ? s : -s;
        const float A1 = tau ? -s : s, B1 = c;
#pragma unroll
        for (int r = 0; r < 32; ++r) {
            float p = __shfl_xor(a[r], 16);
            float A = (r & 1) ? A1 : A0;
            float B = (r & 1) ? B1 : B0;
            a[r] = A * a[r] + B * p;
        }
    }
    // q20..23: tgt = lane bit (8,4,2,1), ctrl = lane bit above it.
    // Masks 8,2,1 go through DPP (VALU); mask 4 through ds_swizzle.
    shfl_gate32<8>(a, scs[10], scc[10], lane);   // q20
    shfl_gate32<4>(a, scs[11], scc[11], lane);   // q21
    shfl_gate32<2>(a, scs[12], scc[12], lane);   // q22
    shfl_gate32<1>(a, scs[13], scc[13], lane);   // q23

    if (SQUARE) {
#pragma unroll
        for (int r = 0; r < 32; ++r) a[r] *= a[r];
    }

    // store STANDARD from L1 (14-bit in-chunk addr):
    // addr = e0..4 | e5..8(k&15)<<5 | e9(lane5)<<9 | e10..12(w)<<10 | e13(k4)<<13
#pragma unroll
    for (int k = 0; k < 32; ++k)
        base[(lane & 31) | ((k & 15) << 5) | (((lane >> 5) & 1) << 9)
             | (w << 10) | (((k >> 4) & 1) << 13)] = a[k];
}

// P23: read pi2 from src, write standard to dst. chunk = e14..23 identity.
template <bool SQUARE>
__global__ __launch_bounds__(512, 4)
void pass23_pi_kernel(const float* __restrict__ src, float* __restrict__ dst,
                      const float* __restrict__ angles, int blk_b) {
    __shared__ float lds[8192];
    __shared__ float scs[14], scc[14];
    const int tid  = threadIdx.x;
    const int lane = tid & 63;
    const int w    = tid >> 6;
    const int chunk = blockIdx.x;                // 10 bits, bit k = e(14+k)
    float* __restrict__ base = dst + ((size_t)chunk << 14);
    const int c14 = chunk & 1;                   // e14
    const float* ang = angles + blk_b * N_QUBITS;

    if (tid < 14) {
        float s, c;
        sincosf(0.5f * ang[10 + tid], &s, &c);
        scs[tid] = s; scc[tid] = c;
    }

    float a[32];
    // read pi2: addr = (blk = r<<4 | w<<1 | e5)<<15 | chunk<<5 | e0..4
#pragma unroll
    for (int r = 0; r < 32; ++r)
        a[r] = src[((size_t)((r << 4) | (w << 1) | (lane >> 5)) << 15)
                   | ((size_t)chunk << 5) | (size_t)(lane & 31)];
    __syncthreads();                             // table ready

    p23_tail<SQUARE>(a, lds, base, scs, scc, lane, w, c14);
}

extern "C" void kernel_launch(void* const* d_in, const int* in_sizes, int n_in,
                              void* d_out, int out_size, void* d_ws, size_t ws_size,
                              hipStream_t stream) {
    const float* angles = (const float*)d_in[0];
    float* out = (float*)d_out;
    float* ws  = (float*)d_ws;

    // block 0 (analytic) + block 1 qubits 0..9 -> ws (pi2); no global reads
    fused_init_p1_kernel<<<512, 1024, 0, stream>>>(ws, angles);
    pass23_pi_kernel<false><<<1024, 512, 0, stream>>>(ws, out, angles, 1);

    pass1_pi_kernel<<<512, 1024, 0, stream>>>(out, ws, angles, 2);
    pass23_pi_kernel<false><<<1024, 512, 0, stream>>>(ws, out, angles, 2);

    pass1_pi_kernel<<<512, 1024, 0, stream>>>(out, ws, angles, 3);
    pass23_pi_kernel<true><<<1024, 512, 0, stream>>>(ws, out, angles, 3);
}